// Round 2
// baseline (19190.164 us; speedup 1.0000x reference)
//
#include <hip/hip_runtime.h>
#include <hip/hip_cooperative_groups.h>

namespace cg = cooperative_groups;

// ============================================================================
// Conv2Seq: conv stack -> enc ; 60-step attentive 3-layer LSTM.
// Round 1: persistent cooperative kernel for the recurrence (4 grid syncs/step
// instead of 8 kernel launches/step), LSTM cell fused into GEMM epilogue.
// Attention trick: keys never materialized; q = W^T h, score = enc . q.
// ============================================================================

#define BB   32
#define TT   2048
#define DIN  64
#define HH   1024
#define DOUT 64
#define NSTEP 60
#define LL1  2045
#define LL2  2038
#define LL3  2023
#define CC1  8
#define CC2  16
#define CC3  32

__device__ __forceinline__ float4 ld4(const float* p){ return *(const float4*)p; }

// ---------------------------------------------------------------------------
// conv kernels (one-shot, unchanged from round 0)
// ---------------------------------------------------------------------------
__global__ __launch_bounds__(256) void conv1_kernel(const float* __restrict__ x,
    const float* __restrict__ w, const float* __restrict__ bias,
    float* __restrict__ out){
  int idx = blockIdx.x*256 + threadIdx.x;
  if (idx >= BB*LL1) return;
  int b = idx / LL1, t = idx % LL1;
  float acc[CC1];
  #pragma unroll
  for (int c=0;c<CC1;++c) acc[c] = bias[c];
  for (int k=0;k<4;++k){
    const float* xr = x + ((size_t)(b*TT + t + k))*DIN;
    for (int d=0; d<DIN; d+=4){
      float4 v = ld4(xr + d);
      #pragma unroll
      for (int c=0;c<CC1;++c){
        acc[c] += v.x * w[((c*DIN+d  )<<2)+k]
                + v.y * w[((c*DIN+d+1)<<2)+k]
                + v.z * w[((c*DIN+d+2)<<2)+k]
                + v.w * w[((c*DIN+d+3)<<2)+k];
      }
    }
  }
  float* o = out + (size_t)idx*CC1;
  #pragma unroll
  for (int c=0;c<CC1;++c) o[c] = fmaxf(acc[c], 0.f);
}

__global__ __launch_bounds__(256) void conv2_kernel(const float* __restrict__ r1,
    const float* __restrict__ w, const float* __restrict__ bias,
    float* __restrict__ out){
  int idx = blockIdx.x*256 + threadIdx.x;
  if (idx >= BB*LL2) return;
  int b = idx / LL2, t = idx % LL2;
  float acc[CC2];
  #pragma unroll
  for (int c=0;c<CC2;++c) acc[c] = bias[c];
  for (int k=0;k<8;++k){
    const float* rr = r1 + ((size_t)(b*LL1 + t + k))*CC1;
    for (int c1=0;c1<CC1;c1+=4){
      float4 v = ld4(rr + c1);
      #pragma unroll
      for (int c=0;c<CC2;++c){
        acc[c] += v.x * w[((c*CC1+c1  )<<3)+k]
                + v.y * w[((c*CC1+c1+1)<<3)+k]
                + v.z * w[((c*CC1+c1+2)<<3)+k]
                + v.w * w[((c*CC1+c1+3)<<3)+k];
      }
    }
  }
  float* o = out + (size_t)idx*CC2;
  #pragma unroll
  for (int c=0;c<CC2;++c) o[c] = fmaxf(acc[c], 0.f);
}

__global__ __launch_bounds__(256) void conv3_kernel(const float* __restrict__ r2,
    const float* __restrict__ w, const float* __restrict__ bias,
    float* __restrict__ out){
  int idx = blockIdx.x*256 + threadIdx.x;
  if (idx >= BB*LL3) return;
  int b = idx / LL3, t = idx % LL3;
  float acc[CC3];
  #pragma unroll
  for (int c=0;c<CC3;++c) acc[c] = bias[c];
  for (int k=0;k<16;++k){
    const float* rr = r2 + ((size_t)(b*LL2 + t + k))*CC2;
    for (int c2=0;c2<CC2;c2+=4){
      float4 v = ld4(rr + c2);
      #pragma unroll
      for (int c=0;c<CC3;++c){
        acc[c] += v.x * w[((c*CC2+c2  )<<4)+k]
                + v.y * w[((c*CC2+c2+1)<<4)+k]
                + v.z * w[((c*CC2+c2+2)<<4)+k]
                + v.w * w[((c*CC2+c2+3)<<4)+k];
      }
    }
  }
  float* o = out + (size_t)idx*CC3;
  #pragma unroll
  for (int c=0;c<CC3;++c) o[c] = fmaxf(acc[c], 0.f);
}

// ---------------------------------------------------------------------------
// Persistent sequence kernel
// ---------------------------------------------------------------------------
struct SeqArgs {
  const float *x;
  const float *wa1, *wa2, *wa3;
  const float *wih1,*whh1,*bih1,*bhh1;
  const float *wih2,*whh2,*bih2,*bhh2;
  const float *wih3,*whh3,*bih3,*bhh3;
  const float *wout,*bout;
  const float *enc;
  float *hbuf;   // [3][2][B][H]
  float *cbuf;   // [3][B][H]
  float *prev;   // [2][B][64]
  float *ctx;    // [3][B][32]
  float *dout;   // [B][60][64]
};

#define SMEM_FLOATS 3840

// attend for (l,b): q = wa^T h ; softmax over enc.q ; ctx = p.enc
__device__ void attend_phase(const SeqArgs& A, int p, float* sm){
  const int bid = blockIdx.x, tid = threadIdx.x;
  const int l = bid >> 5, b = bid & 31;
  const float* wa = (l==0) ? A.wa1 : ((l==1) ? A.wa2 : A.wa3);
  const float* h  = A.hbuf + (size_t)((l*2 + p)*BB + b)*HH;
  float* sh  = sm;           // 1024
  float* sq  = sm + 1024;    // 32
  float* ss  = sm + 1056;    // 2023 (pad to 2024)
  float* red = sm + 3080;    // 256

  *(float4*)&sh[tid*4] = ld4(h + tid*4);
  __syncthreads();

  const int cc = tid & 31, g = tid >> 5;
  float part = 0.f;
  for (int kk = g; kk < HH; kk += 8) part += wa[kk*32 + cc] * sh[kk];
  red[tid] = part; __syncthreads();
  if (tid < 32){ float s = 0.f;
    #pragma unroll
    for (int gg=0; gg<8; ++gg) s += red[gg*32 + tid];
    sq[tid] = s; }
  __syncthreads();

  const float* eb = A.enc + (size_t)b*LL3*CC3;
  float lmax = -1e30f;
  for (int t = tid; t < LL3; t += 256){
    const float* er = eb + t*32;
    float dot = 0.f;
    #pragma unroll
    for (int c=0;c<32;c+=4){ float4 v = ld4(er+c);
      dot += v.x*sq[c] + v.y*sq[c+1] + v.z*sq[c+2] + v.w*sq[c+3]; }
    ss[t] = dot; lmax = fmaxf(lmax, dot);
  }
  red[tid] = lmax; __syncthreads();
  for (int st=128; st>0; st>>=1){ if (tid<st) red[tid] = fmaxf(red[tid], red[tid+st]); __syncthreads(); }
  float m = red[0]; __syncthreads();

  float lsum = 0.f;
  for (int t = tid; t < LL3; t += 256){ float e = __expf(ss[t]-m); ss[t] = e; lsum += e; }
  red[tid] = lsum; __syncthreads();
  for (int st=128; st>0; st>>=1){ if (tid<st) red[tid] += red[tid+st]; __syncthreads(); }
  float rZ = 1.0f / red[0]; __syncthreads();

  float acc = 0.f;
  for (int t = g; t < LL3; t += 8) acc += ss[t] * eb[t*32 + cc];
  red[tid] = acc; __syncthreads();
  if (tid < 32){ float s = 0.f;
    #pragma unroll
    for (int gg=0; gg<8; ++gg) s += red[gg*32 + tid];
    A.ctx[(l*BB + b)*32 + tid] = s * rZ; }
}

// y(sIdx) = h3 @ wout^T + bout ; also prev (if wprev)
__device__ void out_phase(const SeqArgs& A, const float* h3, int sIdx,
                          int pWrite, bool wprev, float* sm, int b){
  float* sh  = sm;         // 1024
  float* red = sm + 1024;  // 256
  const int tid = threadIdx.x;
  *(float4*)&sh[tid*4] = ld4(h3 + (size_t)b*HH + tid*4);
  __syncthreads();
  const int d = tid & 63, kg = tid >> 6;
  const float* wr = A.wout + (size_t)d*HH + kg*256;
  const float* hh = sh + kg*256;
  float acc = 0.f;
  for (int k=0;k<256;k+=4){
    float4 w4 = ld4(wr+k); float4 hv = *(const float4*)&hh[k];
    acc += w4.x*hv.x + w4.y*hv.y + w4.z*hv.z + w4.w*hv.w;
  }
  red[tid] = acc; __syncthreads();
  if (tid < 64){
    float y = red[tid] + red[tid+64] + red[tid+128] + red[tid+192] + A.bout[tid];
    A.dout[((size_t)b*NSTEP + sIdx)*DOUT + tid] = y;
    if (wprev) A.prev[pWrite*BB*DOUT + b*DOUT + tid] = y;
  }
}

// GEMM (16 gate-rows x 32 batch, full K) + fused LSTM cell epilogue.
// block bid covers j in [bid*4, bid*4+4), all 4 gates.
__device__ void gemm_cell(const float* __restrict__ ctxg,
    const float* __restrict__ z, int Kz,
    const float* __restrict__ hold,
    const float* __restrict__ wih, const float* __restrict__ whh,
    const float* __restrict__ bih, const float* __restrict__ bhh,
    float* __restrict__ cbuf, float* __restrict__ hnew, float* sm){
  const int tid = threadIdx.x, bid = blockIdx.x;
  const int Kih = 32 + Kz, Kin = Kih + HH;
  float (*lin)[68] = (float(*)[68])sm;              // 32*68 = 2176
  float (*lw)[68]  = (float(*)[68])(sm + 2176);     // 16*68 = 1088
  float* sg        = sm + 2176 + 1088;              // 16*32 = 512

  const int b = tid & 31, rr = tid >> 5;            // rows rr, rr+8
  const int j0 = bid*4;
  const int rloc = tid >> 4, kc = tid & 15;         // weight staging
  const int grow = ((rloc>>2)<<10) + j0 + (rloc&3); // gate*1024 + j0 + jj
  float a0[4] = {0,0,0,0}, a1[4] = {0,0,0,0};
  const int nT = (Kin + 63) >> 6;

  for (int t = 0; t < nT; ++t){
    const int k0 = t*64;
    #pragma unroll
    for (int i=0;i<2;++i){
      int slot = tid + 256*i;
      int bb = slot >> 4, kk2 = slot & 15;
      int k = k0 + kk2*4;
      float4 v = make_float4(0.f,0.f,0.f,0.f);
      if (k < 32)       v = ld4(ctxg + bb*32 + k);
      else if (k < Kih) v = ld4(z + (size_t)bb*Kz + (k-32));
      else if (k < Kin) v = ld4(hold + (size_t)bb*HH + (k-Kih));
      *(float4*)&lin[bb][kk2*4] = v;
    }
    {
      int k = k0 + kc*4;
      float4 v = make_float4(0.f,0.f,0.f,0.f);
      if (k < Kih)      v = ld4(wih + (size_t)grow*Kih + k);
      else if (k < Kin) v = ld4(whh + (size_t)grow*HH + (k-Kih));
      *(float4*)&lw[rloc][kc*4] = v;
    }
    __syncthreads();
    #pragma unroll
    for (int kk=0; kk<16; ++kk){
      float4 av = *(const float4*)&lin[b][kk*4];
      float4 w0 = *(const float4*)&lw[rr][kk*4];
      float4 w1 = *(const float4*)&lw[rr+8][kk*4];
      a0[kk&3] += av.x*w0.x + av.y*w0.y + av.z*w0.z + av.w*w0.w;
      a1[kk&3] += av.x*w1.x + av.y*w1.y + av.z*w1.z + av.w*w1.w;
    }
    __syncthreads();
  }
  sg[rr*32 + b]     = a0[0]+a0[1]+a0[2]+a0[3];
  sg[(rr+8)*32 + b] = a1[0]+a1[1]+a1[2]+a1[3];
  __syncthreads();
  if (tid < 128){
    const int bb = tid & 31, jj = tid >> 5;
    const int j = j0 + jj;
    float gi = sg[jj*32+bb]      + bih[j]        + bhh[j];
    float gf = sg[(4+jj)*32+bb]  + bih[1024+j]   + bhh[1024+j];
    float gg = sg[(8+jj)*32+bb]  + bih[2048+j]   + bhh[2048+j];
    float go = sg[(12+jj)*32+bb] + bih[3072+j]   + bhh[3072+j];
    float i_ = 1.f/(1.f+__expf(-gi));
    float f_ = 1.f/(1.f+__expf(-gf));
    float g_ = tanhf(gg);
    float o_ = 1.f/(1.f+__expf(-go));
    float c  = f_*cbuf[bb*HH + j] + i_*g_;
    cbuf[bb*HH + j] = c;
    hnew[bb*HH + j] = o_*tanhf(c);
  }
}

__global__ __launch_bounds__(256, 1) void seq_kernel(SeqArgs A){
  cg::grid_group grid = cg::this_grid();
  __shared__ float sm[SMEM_FLOATS];
  const int bid = blockIdx.x, tid = threadIdx.x;

  // init: zero h(parity0) and c; prev[0] = x[:, T-1, :]
  for (int idx = bid*256 + tid; idx < 3*BB*HH; idx += 256*256){
    int l = idx/(BB*HH), r = idx%(BB*HH);
    A.hbuf[(l*2+0)*BB*HH + r] = 0.f;
    A.cbuf[idx] = 0.f;
  }
  if (bid == 0){
    for (int i = tid; i < BB*DIN; i += 256){
      int b = i >> 6, d = i & 63;
      A.prev[i] = A.x[((size_t)b*TT + (TT-1))*DIN + d];
    }
  }
  grid.sync();

  for (int s = 0; s < NSTEP; ++s){
    const int p = s & 1, pn = p ^ 1;

    // Phase A: attend (blocks 0..95) + previous step's output (96..127)
    if (bid < 96)      attend_phase(A, p, sm);
    else if (bid < 128 && s > 0)
      out_phase(A, A.hbuf + (size_t)(2*2 + p)*BB*HH, s-1, p, true, sm, bid-96);
    grid.sync();

    // G1: layer 1, in = [ctx1 | prev(64) | h1_old]
    gemm_cell(A.ctx + 0*BB*32, A.prev + p*BB*DIN, DIN,
              A.hbuf + (size_t)(0*2+p)*BB*HH, A.wih1, A.whh1, A.bih1, A.bhh1,
              A.cbuf + 0*BB*HH, A.hbuf + (size_t)(0*2+pn)*BB*HH, sm);
    grid.sync();

    // G2: layer 2, in = [ctx2 | h1_new(1024) | h2_old]
    gemm_cell(A.ctx + 1*BB*32, A.hbuf + (size_t)(0*2+pn)*BB*HH, HH,
              A.hbuf + (size_t)(1*2+p)*BB*HH, A.wih2, A.whh2, A.bih2, A.bhh2,
              A.cbuf + 1*BB*HH, A.hbuf + (size_t)(1*2+pn)*BB*HH, sm);
    grid.sync();

    // G3: layer 3, in = [ctx3 | h2_new(1024) | h3_old]
    gemm_cell(A.ctx + 2*BB*32, A.hbuf + (size_t)(1*2+pn)*BB*HH, HH,
              A.hbuf + (size_t)(2*2+p)*BB*HH, A.wih3, A.whh3, A.bih3, A.bhh3,
              A.cbuf + 2*BB*HH, A.hbuf + (size_t)(2*2+pn)*BB*HH, sm);
    grid.sync();
  }

  // final output: y(59) from h3 (parity pn(59) = 0 = p(60))
  if (bid >= 96 && bid < 128)
    out_phase(A, A.hbuf + (size_t)(2*2 + 0)*BB*HH, NSTEP-1, 0, false, sm, bid-96);
}

// ---------------------------------------------------------------------------
extern "C" void kernel_launch(void* const* d_in, const int* in_sizes, int n_in,
                              void* d_out, int out_size, void* d_ws, size_t ws_size,
                              hipStream_t stream) {
  const float* x    = (const float*)d_in[0];
  const float* w_c1 = (const float*)d_in[1];
  const float* b_c1 = (const float*)d_in[2];
  const float* w_c2 = (const float*)d_in[3];
  const float* b_c2 = (const float*)d_in[4];
  const float* w_c3 = (const float*)d_in[5];
  const float* b_c3 = (const float*)d_in[6];

  SeqArgs A;
  A.x    = x;
  A.wa1  = (const float*)d_in[7];
  A.wa2  = (const float*)d_in[9];
  A.wa3  = (const float*)d_in[11];
  A.wih1 = (const float*)d_in[13];
  A.whh1 = (const float*)d_in[14];
  A.bih1 = (const float*)d_in[15];
  A.bhh1 = (const float*)d_in[16];
  A.wih2 = (const float*)d_in[17];
  A.whh2 = (const float*)d_in[18];
  A.bih2 = (const float*)d_in[19];
  A.bhh2 = (const float*)d_in[20];
  A.wih3 = (const float*)d_in[21];
  A.whh3 = (const float*)d_in[22];
  A.bih3 = (const float*)d_in[23];
  A.bhh3 = (const float*)d_in[24];
  A.wout = (const float*)d_in[25];
  A.bout = (const float*)d_in[26];

  float* ws = (float*)d_ws;
  size_t off = 0;
  float* enc  = ws + off; off += (size_t)BB*LL3*CC3;
  float* r1   = ws + off; off += (size_t)BB*LL1*CC1;
  float* r2   = ws + off; off += (size_t)BB*LL2*CC2;
  A.hbuf = ws + off; off += (size_t)3*2*BB*HH;
  A.cbuf = ws + off; off += (size_t)3*BB*HH;
  A.prev = ws + off; off += (size_t)2*BB*DIN;
  A.ctx  = ws + off; off += (size_t)3*BB*32;
  A.enc  = enc;
  A.dout = (float*)d_out;

  conv1_kernel<<<(BB*LL1+255)/256, 256, 0, stream>>>(x, w_c1, b_c1, r1);
  conv2_kernel<<<(BB*LL2+255)/256, 256, 0, stream>>>(r1, w_c2, b_c2, r2);
  conv3_kernel<<<(BB*LL3+255)/256, 256, 0, stream>>>(r2, w_c3, b_c3, enc);

  void* params[] = { (void*)&A };
  hipLaunchCooperativeKernel((const void*)seq_kernel, dim3(256), dim3(256),
                             params, 0, stream);
}

// Round 3
// 11320.803 us; speedup vs baseline: 1.6951x; 1.6951x over previous
//
#include <hip/hip_runtime.h>
#include <hip/hip_cooperative_groups.h>

namespace cg = cooperative_groups;

// ============================================================================
// Conv2Seq round 2: persistent coop kernel, 1024 thr/block, MFMA hi/lo-bf16
// split GEMMs (error ~2^-18), fragments straight from global, fused cell.
// Attention trick: keys never materialized; q = W^T h, score = enc . q.
// ============================================================================

#define BB   32
#define TT   2048
#define DIN  64
#define HH   1024
#define DOUT 64
#define NSTEP 60
#define LL1  2045
#define LL2  2038
#define LL3  2023
#define CC1  8
#define CC2  16
#define CC3  32

typedef unsigned short u16;
typedef __attribute__((ext_vector_type(8))) short bf16x8;
typedef __attribute__((ext_vector_type(4))) float f32x4;

__device__ __forceinline__ float4 ld4(const float* p){ return *(const float4*)p; }
__device__ __forceinline__ u16 f2bf(float x){
  unsigned u = __float_as_uint(x);
  return (u16)((u + 0x7FFFu + ((u>>16)&1u)) >> 16);
}
__device__ __forceinline__ float bf2f(u16 h){ return __uint_as_float(((unsigned)h)<<16); }

// ---------------------------------------------------------------------------
// conv kernels (one-shot)
// ---------------------------------------------------------------------------
__global__ __launch_bounds__(256) void conv1_kernel(const float* __restrict__ x,
    const float* __restrict__ w, const float* __restrict__ bias,
    float* __restrict__ out){
  int idx = blockIdx.x*256 + threadIdx.x;
  if (idx >= BB*LL1) return;
  int b = idx / LL1, t = idx % LL1;
  float acc[CC1];
  #pragma unroll
  for (int c=0;c<CC1;++c) acc[c] = bias[c];
  for (int k=0;k<4;++k){
    const float* xr = x + ((size_t)(b*TT + t + k))*DIN;
    for (int d=0; d<DIN; d+=4){
      float4 v = ld4(xr + d);
      #pragma unroll
      for (int c=0;c<CC1;++c){
        acc[c] += v.x * w[((c*DIN+d  )<<2)+k]
                + v.y * w[((c*DIN+d+1)<<2)+k]
                + v.z * w[((c*DIN+d+2)<<2)+k]
                + v.w * w[((c*DIN+d+3)<<2)+k];
      }
    }
  }
  float* o = out + (size_t)idx*CC1;
  #pragma unroll
  for (int c=0;c<CC1;++c) o[c] = fmaxf(acc[c], 0.f);
}

__global__ __launch_bounds__(256) void conv2_kernel(const float* __restrict__ r1,
    const float* __restrict__ w, const float* __restrict__ bias,
    float* __restrict__ out){
  int idx = blockIdx.x*256 + threadIdx.x;
  if (idx >= BB*LL2) return;
  int b = idx / LL2, t = idx % LL2;
  float acc[CC2];
  #pragma unroll
  for (int c=0;c<CC2;++c) acc[c] = bias[c];
  for (int k=0;k<8;++k){
    const float* rr = r1 + ((size_t)(b*LL1 + t + k))*CC1;
    for (int c1=0;c1<CC1;c1+=4){
      float4 v = ld4(rr + c1);
      #pragma unroll
      for (int c=0;c<CC2;++c){
        acc[c] += v.x * w[((c*CC1+c1  )<<3)+k]
                + v.y * w[((c*CC1+c1+1)<<3)+k]
                + v.z * w[((c*CC1+c1+2)<<3)+k]
                + v.w * w[((c*CC1+c1+3)<<3)+k];
      }
    }
  }
  float* o = out + (size_t)idx*CC2;
  #pragma unroll
  for (int c=0;c<CC2;++c) o[c] = fmaxf(acc[c], 0.f);
}

__global__ __launch_bounds__(256) void conv3_kernel(const float* __restrict__ r2,
    const float* __restrict__ w, const float* __restrict__ bias,
    float* __restrict__ out){
  int idx = blockIdx.x*256 + threadIdx.x;
  if (idx >= BB*LL3) return;
  int b = idx / LL3, t = idx % LL3;
  float acc[CC3];
  #pragma unroll
  for (int c=0;c<CC3;++c) acc[c] = bias[c];
  for (int k=0;k<16;++k){
    const float* rr = r2 + ((size_t)(b*LL2 + t + k))*CC2;
    for (int c2=0;c2<CC2;c2+=4){
      float4 v = ld4(rr + c2);
      #pragma unroll
      for (int c=0;c<CC3;++c){
        acc[c] += v.x * w[((c*CC2+c2  )<<4)+k]
                + v.y * w[((c*CC2+c2+1)<<4)+k]
                + v.z * w[((c*CC2+c2+2)<<4)+k]
                + v.w * w[((c*CC2+c2+3)<<4)+k];
      }
    }
  }
  float* o = out + (size_t)idx*CC3;
  #pragma unroll
  for (int c=0;c<CC3;++c) o[c] = fmaxf(acc[c], 0.f);
}

// ---------------------------------------------------------------------------
// weight split prep: w = hi(bf16) + lo(bf16); rows reordered block-major:
// rblk = bid*16 + gate*4 + jj  <->  grow = gate*1024 + bid*4 + jj
// k-order: [wih row (Kih)] ++ [whh row (1024)]
// ---------------------------------------------------------------------------
__global__ __launch_bounds__(256) void prep_kernel(const float* __restrict__ wih,
    const float* __restrict__ whh, u16* __restrict__ wh, u16* __restrict__ wl,
    int Kih, int Kin){
  const int total = 4096*Kin;
  for (int idx = blockIdx.x*256 + threadIdx.x; idx < total; idx += gridDim.x*256){
    int rblk = idx / Kin, k = idx - rblk*Kin;
    int bid = rblk >> 4, rl = rblk & 15, g = rl >> 2, jj = rl & 3;
    int grow = g*1024 + bid*4 + jj;
    float v = (k < Kih) ? wih[(size_t)grow*Kih + k] : whh[(size_t)grow*HH + (k - Kih)];
    u16 h = f2bf(v);
    wh[idx] = h;
    wl[idx] = f2bf(v - bf2f(h));
  }
}

// ---------------------------------------------------------------------------
// Persistent sequence kernel
// ---------------------------------------------------------------------------
struct SeqArgs {
  const float *x;
  const float *wa1,*wa2,*wa3;
  const float *bih1,*bhh1,*bih2,*bhh2,*bih3,*bhh3;
  const float *wout,*bout;
  const float *enc;
  const u16 *wh1,*wl1,*wh2,*wl2,*wh3,*wl3;
  u16 *pl[3][2][2];   // [layer][parity][hi/lo] -> [32][Kin] : [ctx32|z|hold1024]
  float *hbuf;        // [3][2][B][H] fp32 (for attend q)
  float *cbuf;        // [3][B][H]
  float *dout;        // [B][60][64]
};

#define SMEM_FLOATS 8704

// attend for (l,b): q = wa^T h ; softmax over enc.q ; ctx -> plane[l][p] hi/lo
__device__ void attend_phase(const SeqArgs& A, int p, float* sm){
  const int bid = blockIdx.x, tid = threadIdx.x;
  const int l = bid >> 5, b = bid & 31;
  const float* wa = (l==0)?A.wa1:((l==1)?A.wa2:A.wa3);
  const float* h  = A.hbuf + (size_t)((l*2+p)*BB + b)*HH;
  const int Kin = (l==0)?1120:2080;
  u16* ch = A.pl[l][p][0];
  u16* cl = A.pl[l][p][1];
  float* sh  = sm;         // 1024
  float* sq  = sm+1024;    // 32
  float* ss  = sm+1056;    // 2023
  float* red = sm+3104;    // 1024

  sh[tid] = h[tid];
  __syncthreads();

  const int cc = tid&31, g = tid>>5;
  float part = 0.f;
  for (int kk=g; kk<HH; kk+=32) part += wa[kk*32+cc]*sh[kk];
  red[tid] = part; __syncthreads();
  if (tid<32){ float s=0.f;
    #pragma unroll
    for (int gg=0; gg<32; ++gg) s += red[gg*32+tid];
    sq[tid]=s; }
  __syncthreads();

  const float* eb = A.enc + (size_t)b*LL3*CC3;
  float lmax = -1e30f;
  for (int t=tid; t<LL3; t+=1024){
    const float* er = eb + t*32; float dot=0.f;
    #pragma unroll
    for (int c=0;c<32;c+=4){ float4 v=ld4(er+c);
      dot += v.x*sq[c]+v.y*sq[c+1]+v.z*sq[c+2]+v.w*sq[c+3]; }
    ss[t]=dot; lmax=fmaxf(lmax,dot);
  }
  #pragma unroll
  for (int o=32;o>0;o>>=1) lmax = fmaxf(lmax, __shfl_xor(lmax,o));
  if ((tid&63)==0) red[tid>>6] = lmax;
  __syncthreads();
  if (tid==0){ float m=red[0]; for (int w=1;w<16;++w) m=fmaxf(m,red[w]); red[16]=m; }
  __syncthreads();
  const float m = red[16];

  float lsum = 0.f;
  for (int t=tid; t<LL3; t+=1024){ float e=__expf(ss[t]-m); ss[t]=e; lsum+=e; }
  #pragma unroll
  for (int o=32;o>0;o>>=1) lsum += __shfl_xor(lsum,o);
  if ((tid&63)==0) red[32 + (tid>>6)] = lsum;
  __syncthreads();
  if (tid==0){ float z=0.f; for (int w=0;w<16;++w) z+=red[32+w]; red[17]=1.0f/z; }
  __syncthreads();
  const float rZ = red[17];

  float acc = 0.f;
  for (int t=g; t<LL3; t+=32) acc += ss[t]*eb[t*32+cc];
  __syncthreads();
  red[tid] = acc; __syncthreads();
  if (tid<32){ float s=0.f;
    #pragma unroll
    for (int gg=0; gg<32; ++gg) s += red[gg*32+tid];
    float v = s*rZ;
    u16 hh_ = f2bf(v);
    ch[(size_t)b*Kin + tid] = hh_;
    cl[(size_t)b*Kin + tid] = f2bf(v - bf2f(hh_));
  }
}

// y(sIdx) = h3(par) @ wout^T + bout -> dout; optionally prev-slice of plane1[par]
__device__ void out_phase(const SeqArgs& A, int sIdx, int par, bool wprev,
                          float* sm, int b){
  float* sh = sm; float* red = sm+1024;
  const int tid = threadIdx.x;
  const float* h3 = A.hbuf + (size_t)((2*2+par)*BB + b)*HH;
  sh[tid] = h3[tid];
  __syncthreads();
  const int d = tid&63, kg = tid>>6;
  const float* wr = A.wout + (size_t)d*HH + kg*64;
  const float* hh = sh + kg*64;
  float acc = 0.f;
  #pragma unroll
  for (int k=0;k<64;k+=4){ float4 w4=ld4(wr+k); float4 hv=*(const float4*)&hh[k];
    acc += w4.x*hv.x+w4.y*hv.y+w4.z*hv.z+w4.w*hv.w; }
  red[tid]=acc; __syncthreads();
  if (tid<64){
    float y = A.bout[tid];
    #pragma unroll
    for (int kk=0;kk<16;++kk) y += red[kk*64+tid];
    A.dout[((size_t)b*NSTEP+sIdx)*DOUT+tid] = y;
    if (wprev){
      u16 hh_=f2bf(y);
      A.pl[0][par][0][(size_t)b*1120 + 32 + tid] = hh_;
      A.pl[0][par][1][(size_t)b*1120 + 32 + tid] = f2bf(y - bf2f(hh_));
    }
  }
}

// MFMA GEMM (16 rows x 32 batch, K split over 16 waves) + fused LSTM cell.
// hi/lo bf16 split: x.w ~= xh.wh + xh.wl + xl.wh  (error ~2^-18)
__device__ void gemm_phase(const SeqArgs& A, int l, int p, int pn, float* sm){
  const int tid = threadIdx.x, bid = blockIdx.x;
  const int Kin = (l==0)?1120:2080;
  const int Kz  = (l==0)?64:1024;
  const u16* wh = (l==0)?A.wh1:((l==1)?A.wh2:A.wh3);
  const u16* wl = (l==0)?A.wl1:((l==1)?A.wl2:A.wl3);
  const float* bih = (l==0)?A.bih1:((l==1)?A.bih2:A.bih3);
  const float* bhh = (l==0)?A.bhh1:((l==1)?A.bhh2:A.bhh3);
  const u16* ih = A.pl[l][p][0];
  const u16* il = A.pl[l][p][1];

  const int wave = tid>>6, lane = tid&63;
  const int r15 = lane&15, g8 = (lane>>4)<<3;
  f32x4 acc0 = {0.f,0.f,0.f,0.f}, acc1 = {0.f,0.f,0.f,0.f};
  const u16* wph = wh + (size_t)(bid*16 + r15)*Kin + g8;
  const u16* wpl = wl + (size_t)(bid*16 + r15)*Kin + g8;
  const u16* a0h = ih + (size_t)r15*Kin + g8;
  const u16* a0l = il + (size_t)r15*Kin + g8;
  const u16* a1h = ih + (size_t)(16+r15)*Kin + g8;
  const u16* a1l = il + (size_t)(16+r15)*Kin + g8;
  const int nks = Kin >> 5;
  for (int ks = wave; ks < nks; ks += 16){
    const int k0 = ks<<5;
    bf16x8 bh  = *(const bf16x8*)(wph + k0);
    bf16x8 bl  = *(const bf16x8*)(wpl + k0);
    bf16x8 xh0 = *(const bf16x8*)(a0h + k0);
    bf16x8 xl0 = *(const bf16x8*)(a0l + k0);
    bf16x8 xh1 = *(const bf16x8*)(a1h + k0);
    bf16x8 xl1 = *(const bf16x8*)(a1l + k0);
    acc0 = __builtin_amdgcn_mfma_f32_16x16x32_bf16(xh0, bh, acc0, 0,0,0);
    acc1 = __builtin_amdgcn_mfma_f32_16x16x32_bf16(xh1, bh, acc1, 0,0,0);
    acc0 = __builtin_amdgcn_mfma_f32_16x16x32_bf16(xl0, bh, acc0, 0,0,0);
    acc1 = __builtin_amdgcn_mfma_f32_16x16x32_bf16(xl1, bh, acc1, 0,0,0);
    acc0 = __builtin_amdgcn_mfma_f32_16x16x32_bf16(xh0, bl, acc0, 0,0,0);
    acc1 = __builtin_amdgcn_mfma_f32_16x16x32_bf16(xh1, bl, acc1, 0,0,0);
  }
  float* red = sm; float* sg = sm + 8192;   // red 16x512, sg 512
  #pragma unroll
  for (int rg=0; rg<4; ++rg){
    red[wave*512 +       rg*64 + lane] = acc0[rg];
    red[wave*512 + 256 + rg*64 + lane] = acc1[rg];
  }
  __syncthreads();
  if (tid < 512){
    float s2 = 0.f;
    #pragma unroll
    for (int w=0; w<16; ++w) s2 += red[w*512 + tid];
    // D layout (m89): col = lane&15 (weight row), row = 4*(lane>>4)+reg (batch)
    const int tile = tid>>8, rg=(tid>>6)&3, ln=tid&63;
    const int bb = tile*16 + ((ln>>4)<<2) + rg;
    const int rl = ln&15;
    sg[rl*32 + bb] = s2;
  }
  __syncthreads();
  if (tid < 128){
    const int b = tid&31, jj = tid>>5;
    const int j = bid*4 + jj;
    float gi = sg[jj*32+b]      + bih[j]      + bhh[j];
    float gf = sg[(4+jj)*32+b]  + bih[1024+j] + bhh[1024+j];
    float gg = sg[(8+jj)*32+b]  + bih[2048+j] + bhh[2048+j];
    float go = sg[(12+jj)*32+b] + bih[3072+j] + bhh[3072+j];
    float i_ = 1.f/(1.f+__expf(-gi));
    float f_ = 1.f/(1.f+__expf(-gf));
    float g_ = tanhf(gg);
    float o_ = 1.f/(1.f+__expf(-go));
    float* cb = A.cbuf + ((size_t)l*BB + b)*HH;
    float c = f_*cb[j] + i_*g_;
    cb[j] = c;
    float hval = o_*tanhf(c);
    A.hbuf[((size_t)(l*2+pn)*BB + b)*HH + j] = hval;
    u16 hh_ = f2bf(hval), hl_ = f2bf(hval - bf2f(hh_));
    A.pl[l][pn][0][(size_t)b*Kin + 32 + Kz + j] = hh_;   // own hold slice
    A.pl[l][pn][1][(size_t)b*Kin + 32 + Kz + j] = hl_;
    if (l < 2){                                          // next layer z slice
      A.pl[l+1][p][0][(size_t)b*2080 + 32 + j] = hh_;
      A.pl[l+1][p][1][(size_t)b*2080 + 32 + j] = hl_;
    }
  }
}

__global__ __launch_bounds__(1024, 4) void seq_kernel(SeqArgs A){
  cg::grid_group grid = cg::this_grid();
  __shared__ float sm[SMEM_FLOATS];
  const int bid = blockIdx.x, tid = threadIdx.x;
  const size_t gtid = (size_t)bid*1024 + tid, gstr = (size_t)256*1024;

  // init: zero h(parity0), c, hold slices(parity0); plane1 z(parity0)=x last
  for (size_t i=gtid; i<(size_t)3*BB*HH; i+=gstr){
    size_t l = i/(BB*HH), r = i%(BB*HH);
    A.hbuf[(l*2+0)*(size_t)(BB*HH) + r] = 0.f;
    A.cbuf[i] = 0.f;
  }
  #pragma unroll
  for (int l=0;l<3;++l){
    const int Kin=(l==0)?1120:2080, Kz=(l==0)?64:1024;
    for (size_t i=gtid; i<(size_t)BB*HH; i+=gstr){
      size_t b=i>>10, j=i&1023;
      size_t off=b*Kin + 32 + Kz + j;
      A.pl[l][0][0][off]=0; A.pl[l][0][1][off]=0;
    }
  }
  for (size_t i=gtid; i<(size_t)BB*DIN; i+=gstr){
    size_t b=i>>6, d=i&63;
    float v = A.x[(b*TT + (TT-1))*DIN + d];
    u16 hh_=f2bf(v);
    A.pl[0][0][0][b*1120+32+d]=hh_;
    A.pl[0][0][1][b*1120+32+d]=f2bf(v-bf2f(hh_));
  }
  grid.sync();

  for (int s=0;s<NSTEP;++s){
    const int p=s&1, pn=p^1;
    if (bid<96)                      attend_phase(A,p,sm);
    else if (bid<128 && s>0)         out_phase(A, s-1, p, true, sm, bid-96);
    grid.sync();
    gemm_phase(A,0,p,pn,sm); grid.sync();
    gemm_phase(A,1,p,pn,sm); grid.sync();
    gemm_phase(A,2,p,pn,sm); grid.sync();
  }
  if (bid>=96 && bid<128) out_phase(A, NSTEP-1, 0, false, sm, bid-96);
}

// ---------------------------------------------------------------------------
extern "C" void kernel_launch(void* const* d_in, const int* in_sizes, int n_in,
                              void* d_out, int out_size, void* d_ws, size_t ws_size,
                              hipStream_t stream) {
  const float* x    = (const float*)d_in[0];
  const float* w_c1 = (const float*)d_in[1];
  const float* b_c1 = (const float*)d_in[2];
  const float* w_c2 = (const float*)d_in[3];
  const float* b_c2 = (const float*)d_in[4];
  const float* w_c3 = (const float*)d_in[5];
  const float* b_c3 = (const float*)d_in[6];

  SeqArgs A;
  A.x    = x;
  A.wa1  = (const float*)d_in[7];
  A.wa2  = (const float*)d_in[9];
  A.wa3  = (const float*)d_in[11];
  const float* wih1 = (const float*)d_in[13];
  const float* whh1 = (const float*)d_in[14];
  A.bih1 = (const float*)d_in[15];
  A.bhh1 = (const float*)d_in[16];
  const float* wih2 = (const float*)d_in[17];
  const float* whh2 = (const float*)d_in[18];
  A.bih2 = (const float*)d_in[19];
  A.bhh2 = (const float*)d_in[20];
  const float* wih3 = (const float*)d_in[21];
  const float* whh3 = (const float*)d_in[22];
  A.bih3 = (const float*)d_in[23];
  A.bhh3 = (const float*)d_in[24];
  A.wout = (const float*)d_in[25];
  A.bout = (const float*)d_in[26];
  A.dout = (float*)d_out;

  char* base = (char*)d_ws;
  size_t off = 0;
  auto alloc = [&](size_t bytes)->char*{
    char* pp = base + off; off = (off + bytes + 255) & ~(size_t)255; return pp;
  };

  float* enc = (float*)alloc((size_t)BB*LL3*CC3*4);
  A.enc  = enc;
  A.hbuf = (float*)alloc((size_t)3*2*BB*HH*4);
  A.cbuf = (float*)alloc((size_t)3*BB*HH*4);
  for (int l=0;l<3;++l){
    size_t kin = (l==0)?1120:2080;
    for (int par=0; par<2; ++par)
      for (int hl=0; hl<2; ++hl)
        A.pl[l][par][hl] = (u16*)alloc((size_t)BB*kin*2);
  }
  size_t woff = off;   // weight-split region; conv temps alias it (dead after)
  u16* wh1 = (u16*)alloc((size_t)4096*1120*2);
  u16* wl1 = (u16*)alloc((size_t)4096*1120*2);
  u16* wh2 = (u16*)alloc((size_t)4096*2080*2);
  u16* wl2 = (u16*)alloc((size_t)4096*2080*2);
  u16* wh3 = (u16*)alloc((size_t)4096*2080*2);
  u16* wl3 = (u16*)alloc((size_t)4096*2080*2);
  A.wh1=wh1; A.wl1=wl1; A.wh2=wh2; A.wl2=wl2; A.wh3=wh3; A.wl3=wl3;
  float* r1 = (float*)(base + woff);                       // 2.09 MB
  float* r2 = (float*)(base + woff + ((size_t)2200*1024)); // 4.17 MB

  conv1_kernel<<<(BB*LL1+255)/256, 256, 0, stream>>>(x, w_c1, b_c1, r1);
  conv2_kernel<<<(BB*LL2+255)/256, 256, 0, stream>>>(r1, w_c2, b_c2, r2);
  conv3_kernel<<<(BB*LL3+255)/256, 256, 0, stream>>>(r2, w_c3, b_c3, enc);
  prep_kernel<<<2048, 256, 0, stream>>>(wih1, whh1, wh1, wl1,   96, 1120);
  prep_kernel<<<2048, 256, 0, stream>>>(wih2, whh2, wh2, wl2, 1056, 2080);
  prep_kernel<<<2048, 256, 0, stream>>>(wih3, whh3, wh3, wl3, 1056, 2080);

  void* params[] = { (void*)&A };
  hipLaunchCooperativeKernel((const void*)seq_kernel, dim3(256), dim3(1024),
                             params, 0, stream);
}

// Round 5
// 9773.408 us; speedup vs baseline: 1.9635x; 1.1583x over previous
//
#include <hip/hip_runtime.h>

// ============================================================================
// Conv2Seq round 4: persistent kernel, custom MONOTONIC grid barrier with
// __threadfence() release/acquire (textbook agent-scope coherence), plain
// vectorized loads/stores for all shared state. No W_eff fold (K1=1120),
// y/prev computed in a small 4th phase. Workspace ~93 MB (< R2's passing 97).
// Attention trick: keys never materialized; q = W^T h, score = enc . q.
// GEMMs: MFMA 16x16x32 bf16 with hi/lo split (x.w ~ xh.wh + xl.wh + xh.wl).
// ============================================================================

#define BB   32
#define TT   2048
#define DIN  64
#define HH   1024
#define DOUT 64
#define NSTEP 60
#define LL1  2045
#define LL2  2038
#define LL3  2023
#define CC1  8
#define CC2  16
#define CC3  32
#define K0   1120     // layer1 K: [ctx32 | prev64 | h1 1024]
#define K12  2080     // layers2/3: [ctx32 | h_prev 1024 | h_own 1024]

typedef unsigned short u16;
typedef unsigned int   u32;
typedef unsigned long long u64;
typedef __attribute__((ext_vector_type(8))) short bf16x8;
typedef __attribute__((ext_vector_type(4))) float f32x4;

__device__ __forceinline__ float4 ld4(const float* p){ return *(const float4*)p; }
__device__ __forceinline__ u16 f2bf(float x){
  unsigned u = __float_as_uint(x);
  return (u16)((u + 0x7FFFu + ((u>>16)&1u)) >> 16);
}
__device__ __forceinline__ float bf2f(u16 h){ return __uint_as_float(((unsigned)h)<<16); }
__device__ __forceinline__ float bfq(u64 w, int i){
  return __uint_as_float(((u32)((w >> (16*i)) & 0xffffu)) << 16);
}

// ---------------------------------------------------------------------------
// conv kernels (one-shot; conv3 emits bf16 enc)
// ---------------------------------------------------------------------------
__global__ __launch_bounds__(256) void conv1_kernel(const float* __restrict__ x,
    const float* __restrict__ w, const float* __restrict__ bias,
    float* __restrict__ out){
  int idx = blockIdx.x*256 + threadIdx.x;
  if (idx >= BB*LL1) return;
  int b = idx / LL1, t = idx % LL1;
  float acc[CC1];
  #pragma unroll
  for (int c=0;c<CC1;++c) acc[c] = bias[c];
  for (int k=0;k<4;++k){
    const float* xr = x + ((size_t)(b*TT + t + k))*DIN;
    for (int d=0; d<DIN; d+=4){
      float4 v = ld4(xr + d);
      #pragma unroll
      for (int c=0;c<CC1;++c){
        acc[c] += v.x * w[((c*DIN+d  )<<2)+k]
                + v.y * w[((c*DIN+d+1)<<2)+k]
                + v.z * w[((c*DIN+d+2)<<2)+k]
                + v.w * w[((c*DIN+d+3)<<2)+k];
      }
    }
  }
  float* o = out + (size_t)idx*CC1;
  #pragma unroll
  for (int c=0;c<CC1;++c) o[c] = fmaxf(acc[c], 0.f);
}

__global__ __launch_bounds__(256) void conv2_kernel(const float* __restrict__ r1,
    const float* __restrict__ w, const float* __restrict__ bias,
    float* __restrict__ out){
  int idx = blockIdx.x*256 + threadIdx.x;
  if (idx >= BB*LL2) return;
  int b = idx / LL2, t = idx % LL2;
  float acc[CC2];
  #pragma unroll
  for (int c=0;c<CC2;++c) acc[c] = bias[c];
  for (int k=0;k<8;++k){
    const float* rr = r1 + ((size_t)(b*LL1 + t + k))*CC1;
    for (int c1=0;c1<CC1;c1+=4){
      float4 v = ld4(rr + c1);
      #pragma unroll
      for (int c=0;c<CC2;++c){
        acc[c] += v.x * w[((c*CC1+c1  )<<3)+k]
                + v.y * w[((c*CC1+c1+1)<<3)+k]
                + v.z * w[((c*CC1+c1+2)<<3)+k]
                + v.w * w[((c*CC1+c1+3)<<3)+k];
      }
    }
  }
  float* o = out + (size_t)idx*CC2;
  #pragma unroll
  for (int c=0;c<CC2;++c) o[c] = fmaxf(acc[c], 0.f);
}

__global__ __launch_bounds__(256) void conv3_kernel(const float* __restrict__ r2,
    const float* __restrict__ w, const float* __restrict__ bias,
    u16* __restrict__ out){
  int idx = blockIdx.x*256 + threadIdx.x;
  if (idx >= BB*LL3) return;
  int b = idx / LL3, t = idx % LL3;
  float acc[CC3];
  #pragma unroll
  for (int c=0;c<CC3;++c) acc[c] = bias[c];
  for (int k=0;k<16;++k){
    const float* rr = r2 + ((size_t)(b*LL2 + t + k))*CC2;
    for (int c2=0;c2<CC2;c2+=4){
      float4 v = ld4(rr + c2);
      #pragma unroll
      for (int c=0;c<CC3;++c){
        acc[c] += v.x * w[((c*CC2+c2  )<<4)+k]
                + v.y * w[((c*CC2+c2+1)<<4)+k]
                + v.z * w[((c*CC2+c2+2)<<4)+k]
                + v.w * w[((c*CC2+c2+3)<<4)+k];
      }
    }
  }
  u16* o = out + (size_t)idx*CC3;
  #pragma unroll
  for (int c=0;c<CC3;++c) o[c] = f2bf(fmaxf(acc[c], 0.f));
}

// ---------------------------------------------------------------------------
// weight prep: row reorder rblk = bid*32 + rl, rl = gate*8+jj,
// grow = gate*1024 + bid*8 + jj. K-order: [wih row (Kih)] ++ [whh row (1024)].
// hi/lo bf16 split.
// ---------------------------------------------------------------------------
__global__ __launch_bounds__(256) void prep_kernel(const float* __restrict__ wih,
    const float* __restrict__ whh, u16* __restrict__ wh, u16* __restrict__ wl,
    int Kih, int Kin){
  const size_t total = (size_t)4096*Kin;
  for (size_t idx = (size_t)blockIdx.x*256 + threadIdx.x; idx < total;
       idx += (size_t)gridDim.x*256){
    int rblk = idx / Kin, k = idx - (size_t)rblk*Kin;
    int bid = rblk>>5, rl = rblk&31, g = rl>>3, jj = rl&7;
    int grow = g*1024 + bid*8 + jj;
    float v = (k < Kih) ? wih[(size_t)grow*Kih + k]
                        : whh[(size_t)grow*HH + (k-Kih)];
    u16 h = f2bf(v);
    wh[idx] = h;
    wl[idx] = f2bf(v - bf2f(h));
  }
}

__global__ __launch_bounds__(256) void bsum_kernel(
    const float* __restrict__ bih1, const float* __restrict__ bhh1,
    const float* __restrict__ bih2, const float* __restrict__ bhh2,
    const float* __restrict__ bih3, const float* __restrict__ bhh3,
    float* __restrict__ bs0, float* __restrict__ bs1, float* __restrict__ bs2){
  int idx = blockIdx.x*256 + threadIdx.x;
  if (idx < 4096)       bs0[idx] = bih1[idx] + bhh1[idx];
  else if (idx < 8192){ int r=idx-4096; bs1[r] = bih2[r] + bhh2[r]; }
  else if (idx < 12288){int r=idx-8192; bs2[r] = bih3[r] + bhh3[r]; }
}

__global__ void barinit_kernel(u32* bar){
  if (threadIdx.x < 128) bar[threadIdx.x] = 0u;
}

// ---------------------------------------------------------------------------
// Persistent sequence kernel
// ---------------------------------------------------------------------------
struct SeqArgs {
  const float *x;
  const float *wa[3];
  const float *wout, *bout;
  const u16 *enc;              // [32][2023][32] bf16
  const u16 *wwh[3], *wwl[3];
  const float *bsum[3];
  u16 *pl[3][2][2];            // [layer][parity][hi/lo]
  float *hbuf;                 // [3][2][32][1024]
  float *cbuf;                 // [3][32][1024] (block-private)
  float *dout;                 // [32][60][64]
  u32 *cnt;
};

#define SMEM_FLOATS 5376

// monotonic grid barrier with proper release/acquire fences.
__device__ __forceinline__ void gbar(u32* cnt, u32 target){
  __syncthreads();                 // all waves' vmem drained (implicit vmcnt(0))
  if (threadIdx.x == 0){
    __threadfence();               // release: wb dirty L2 to coherent point
    __hip_atomic_fetch_add(cnt, 1u, __ATOMIC_RELAXED, __HIP_MEMORY_SCOPE_AGENT);
    while (__hip_atomic_load(cnt, __ATOMIC_RELAXED, __HIP_MEMORY_SCOPE_AGENT) < target)
      __builtin_amdgcn_s_sleep(8);
    __threadfence();               // acquire: invalidate L1/L2 before reads
  }
  __syncthreads();
}

// attend for (l,b) parity par: q = wa^T h ; softmax(enc.q) ; ctx -> plane
__device__ void attend_phase(const SeqArgs& A, int l, int par, int b, float* sm){
  const int tid = threadIdx.x;
  const float* wa = A.wa[l];
  const float* h  = A.hbuf + (size_t)((l*2+par)*BB + b)*HH;
  const int Kin = (l==0)? K0 : K12;
  const int str = Kin>>1;          // u32 row stride
  u16* ch = A.pl[l][par][0];
  u16* cl = A.pl[l][par][1];
  float* sh  = sm;          // 1024
  float* sq  = sm + 1024;   // 32
  float* ss  = sm + 1056;   // 2023 (pad 2048)
  float* red = sm + 3104;   // 1024
  float* ctxf= sm + 4128;   // 32

  sh[tid] = h[tid];
  __syncthreads();

  const int cc = tid&31, g = tid>>5;
  float part = 0.f;
  for (int kk=g; kk<HH; kk+=32) part += wa[kk*32+cc]*sh[kk];
  red[tid] = part; __syncthreads();
  if (tid<32){ float s=0.f;
    #pragma unroll
    for (int gg=0; gg<32; ++gg) s += red[gg*32+tid];
    sq[tid]=s; }
  __syncthreads();

  const u16* eb = A.enc + (size_t)b*LL3*CC3;
  float lmax = -1e30f;
  for (int t=tid; t<LL3; t+=1024){
    const u16* er = eb + t*32; float dot=0.f;
    #pragma unroll
    for (int c4=0;c4<8;++c4){
      u64 w = *(const u64*)(er + c4*4);
      dot += bfq(w,0)*sq[c4*4] + bfq(w,1)*sq[c4*4+1]
           + bfq(w,2)*sq[c4*4+2] + bfq(w,3)*sq[c4*4+3];
    }
    ss[t]=dot; lmax=fmaxf(lmax,dot);
  }
  #pragma unroll
  for (int o=32;o>0;o>>=1) lmax = fmaxf(lmax, __shfl_xor(lmax,o));
  if ((tid&63)==0) red[tid>>6] = lmax;
  __syncthreads();
  if (tid==0){ float m=red[0]; for (int w=1;w<16;++w) m=fmaxf(m,red[w]); red[16]=m; }
  __syncthreads();
  const float m = red[16];

  float lsum = 0.f;
  for (int t=tid; t<LL3; t+=1024){ float e=__expf(ss[t]-m); ss[t]=e; lsum+=e; }
  #pragma unroll
  for (int o=32;o>0;o>>=1) lsum += __shfl_xor(lsum,o);
  if ((tid&63)==0) red[32 + (tid>>6)] = lsum;
  __syncthreads();
  if (tid==0){ float z=0.f; for (int w=0;w<16;++w) z+=red[32+w]; red[17]=1.0f/z; }
  __syncthreads();
  const float rZ = red[17];

  float acc = 0.f;
  for (int t=g; t<LL3; t+=32) acc += ss[t]*bf2f(eb[t*32+cc]);
  __syncthreads();
  red[tid] = acc; __syncthreads();
  if (tid<32){ float s=0.f;
    #pragma unroll
    for (int gg=0; gg<32; ++gg) s += red[gg*32+tid];
    ctxf[tid] = s*rZ; }
  __syncthreads();
  if (tid < 16){
    float v0=ctxf[2*tid], v1=ctxf[2*tid+1];
    ((u32*)ch)[(size_t)b*str + tid] = (u32)f2bf(v0) | ((u32)f2bf(v1)<<16);
  } else if (tid < 32){
    int t2 = tid-16;
    float v0=ctxf[2*t2], v1=ctxf[2*t2+1];
    u16 h0=f2bf(v0), h1=f2bf(v1);
    ((u32*)cl)[(size_t)b*str + t2] =
        (u32)f2bf(v0-bf2f(h0)) | ((u32)f2bf(v1-bf2f(h1))<<16);
  }
}

// out phase: y(s) = h3(pn) @ wout^T + bout -> dout[:,s,:] and prev slot of
// layer-1 plane parity pn (consumed by G1(s+1)).
__device__ void out_phase(const SeqArgs& A, int pn, int s, int b, float* sm){
  float* sh = sm; float* red = sm+1024; float* yv = sm+2048;
  const int tid = threadIdx.x;
  sh[tid] = A.hbuf[(size_t)((2*2+pn)*BB + b)*HH + tid];
  __syncthreads();
  const int d = tid&63, kg = tid>>6;
  const float* wr = A.wout + (size_t)d*HH + kg*64;
  const float* hh = sh + kg*64;
  float acc = 0.f;
  #pragma unroll
  for (int k=0;k<64;k+=4){ float4 w4=ld4(wr+k); float4 hv=*(const float4*)&hh[k];
    acc += w4.x*hv.x+w4.y*hv.y+w4.z*hv.z+w4.w*hv.w; }
  red[tid]=acc; __syncthreads();
  if (tid<64){
    float y = A.bout[tid];
    #pragma unroll
    for (int kk=0;kk<16;++kk) y += red[kk*64+tid];
    A.dout[((size_t)b*NSTEP+s)*DOUT+tid] = y;
    yv[tid] = y;
  }
  __syncthreads();
  if (tid < 32){
    float v0=yv[2*tid], v1=yv[2*tid+1];
    ((u32*)A.pl[0][pn][0])[(size_t)b*(K0>>1) + 16 + tid] =
        (u32)f2bf(v0) | ((u32)f2bf(v1)<<16);
  } else if (tid < 64){
    int t2 = tid-32;
    float v0=yv[2*t2], v1=yv[2*t2+1];
    u16 h0=f2bf(v0), h1=f2bf(v1);
    ((u32*)A.pl[0][pn][1])[(size_t)b*(K0>>1) + 16 + t2] =
        (u32)f2bf(v0-bf2f(h0)) | ((u32)f2bf(v1-bf2f(h1))<<16);
  }
}

// MFMA GEMM (32 weight rows x 32 batch per block, 128 blocks) + fused cell.
__device__ void gemm_phase(const SeqArgs& A, int l, int p, int pn, float* sm){
  const int bid = blockIdx.x, tid = threadIdx.x;
  const int Kin = (l==0)? K0 : K12;
  const int nks = Kin >> 5;
  const u16* wh  = A.wwh[l];
  const u16* wlo = A.wwl[l];
  const u16* ih = A.pl[l][p][0];
  const u16* il = A.pl[l][p][1];
  const int wave = tid>>6, lane = tid&63;
  const int wt = wave>>3, xh = (wave>>2)&1, kq = wave&3;
  const int r15 = lane&15, g8 = (lane>>4)<<3;
  const u16* wph = wh  + (size_t)(bid*32 + wt*16 + r15)*Kin + g8;
  const u16* wpl = wlo + (size_t)(bid*32 + wt*16 + r15)*Kin + g8;
  const u16* xph = ih + (size_t)(xh*16 + r15)*Kin + g8;
  const u16* xpl = il + (size_t)(xh*16 + r15)*Kin + g8;

  f32x4 acc = {0.f,0.f,0.f,0.f};
  for (int ks = kq; ks < nks; ks += 4){
    const int o = ks*32;
    bf16x8 bh  = *(const bf16x8*)(wph + o);
    bf16x8 bl  = *(const bf16x8*)(wpl + o);
    bf16x8 xhv = *(const bf16x8*)(xph + o);
    bf16x8 xlv = *(const bf16x8*)(xpl + o);
    acc = __builtin_amdgcn_mfma_f32_16x16x32_bf16(xhv, bh, acc, 0,0,0);
    acc = __builtin_amdgcn_mfma_f32_16x16x32_bf16(xlv, bh, acc, 0,0,0);
    acc = __builtin_amdgcn_mfma_f32_16x16x32_bf16(xhv, bl, acc, 0,0,0);
  }

  float* red = sm;            // 16*256
  float* sg  = sm + 4096;     // 32*32
  float* hv  = sm + 5120;     // 8*32
  #pragma unroll
  for (int rg=0; rg<4; ++rg) red[wave*256 + lane*4 + rg] = acc[rg];
  __syncthreads();
  {
    const int tile = tid>>8, e = tid&255;
    const int wt2 = tile>>1, xh2 = tile&1;
    const int base = (wt2*8 + xh2*4)*256 + e;
    float v = red[base] + red[base+256] + red[base+512] + red[base+768];
    const int ln = e>>2, rg = e&3;
    // D layout (m89): col=lane&15 -> weight row, row=4*(lane>>4)+reg -> batch
    sg[(wt2*16 + (ln&15))*32 + xh2*16 + ((ln>>4)<<2) + rg] = v;
  }
  __syncthreads();
  if (tid < 256){
    const int b = tid&31, jj = tid>>5;
    const int j = bid*8 + jj;
    const float* bs = A.bsum[l];
    float gi = sg[(0 +jj)*32+b] + bs[j];
    float gf = sg[(8 +jj)*32+b] + bs[1024+j];
    float gg = sg[(16+jj)*32+b] + bs[2048+j];
    float go = sg[(24+jj)*32+b] + bs[3072+j];
    float i_ = 1.f/(1.f+__expf(-gi));
    float f_ = 1.f/(1.f+__expf(-gf));
    float g_ = tanhf(gg);
    float o_ = 1.f/(1.f+__expf(-go));
    float* cb = A.cbuf + ((size_t)l*BB + b)*HH + j;
    float c = f_*cb[0] + i_*g_;
    cb[0] = c;
    float hval = o_*tanhf(c);
    A.hbuf[((size_t)(l*2+pn)*BB + b)*HH + j] = hval;
    hv[jj*32 + b] = hval;
  }
  __syncthreads();
  if (tid < 128){
    const int b = tid&31, pr = tid>>5;
    const int jj0 = pr*2;
    float v0 = hv[jj0*32+b], v1 = hv[(jj0+1)*32+b];
    u16 h0 = f2bf(v0), h1 = f2bf(v1);
    u32 ph  = (u32)h0 | ((u32)h1<<16);
    u32 plq = (u32)f2bf(v0-bf2f(h0)) | ((u32)f2bf(v1-bf2f(h1))<<16);
    const int col = bid*8 + jj0;
    if (l == 0){
      size_t i1 = ((size_t)b*K0  + 96   + col) >> 1;   // own h1, next step
      ((u32*)A.pl[0][pn][0])[i1] = ph;  ((u32*)A.pl[0][pn][1])[i1] = plq;
      size_t i2 = ((size_t)b*K12 + 32   + col) >> 1;   // L2 input, this step
      ((u32*)A.pl[1][p ][0])[i2] = ph;  ((u32*)A.pl[1][p ][1])[i2] = plq;
    } else if (l == 1){
      size_t i1 = ((size_t)b*K12 + 1056 + col) >> 1;   // own h2, next step
      ((u32*)A.pl[1][pn][0])[i1] = ph;  ((u32*)A.pl[1][pn][1])[i1] = plq;
      size_t i2 = ((size_t)b*K12 + 32   + col) >> 1;   // L3 input, this step
      ((u32*)A.pl[2][p ][0])[i2] = ph;  ((u32*)A.pl[2][p ][1])[i2] = plq;
    } else {
      size_t i1 = ((size_t)b*K12 + 1056 + col) >> 1;   // own h3, next step
      ((u32*)A.pl[2][pn][0])[i1] = ph;  ((u32*)A.pl[2][pn][1])[i1] = plq;
    }
  }
}

__global__ __launch_bounds__(1024, 4) void seq_kernel(SeqArgs A){
  __shared__ float sm[SMEM_FLOATS];
  const int bid = blockIdx.x, tid = threadIdx.x;
  const size_t gid = (size_t)bid*1024 + tid;
  const size_t gstr = (size_t)256*1024;
  u32 nb = 0;

  // ---- init ----
  // hbuf parity 0 = 0
  for (size_t i = gid; i < (size_t)3*32*1024; i += gstr){
    size_t l2 = i >> 15, r = i & 32767, b = r >> 10, j = r & 1023;
    A.hbuf[((l2*2+0)*BB + b)*HH + j] = 0.f;
  }
  // cbuf = 0 (block-private columns)
  if (bid < 128){
    for (int t = tid; t < 3*32*8; t += 1024){
      int l2 = t/(32*8), r = t%(32*8), b = r>>3, jj = r&7;
      A.cbuf[((size_t)l2*BB + b)*HH + bid*8 + jj] = 0.f;
    }
  }
  // plane parity0 h-slices = 0: l0 u32 [48,560) ; l1/l2 u32 [528,1040)
  for (size_t i = gid; i < (size_t)32*512; i += gstr){
    size_t b = i >> 9, o = i & 511;
    ((u32*)A.pl[0][0][0])[b*(K0>>1) + 48 + o] = 0u;
    ((u32*)A.pl[0][0][1])[b*(K0>>1) + 48 + o] = 0u;
    ((u32*)A.pl[1][0][0])[b*(K12>>1) + 528 + o] = 0u;
    ((u32*)A.pl[1][0][1])[b*(K12>>1) + 528 + o] = 0u;
    ((u32*)A.pl[2][0][0])[b*(K12>>1) + 528 + o] = 0u;
    ((u32*)A.pl[2][0][1])[b*(K12>>1) + 528 + o] = 0u;
  }
  // prev(0) = x[:, T-1, :] into l0 parity0 u16 [32,96)
  for (size_t i = gid; i < (size_t)BB*DIN; i += gstr){
    size_t b = i >> 6, d = i & 63;
    float v = A.x[(b*TT + (TT-1))*DIN + d];
    u16 h = f2bf(v);
    A.pl[0][0][0][b*K0 + 32 + d] = h;
    A.pl[0][0][1][b*K0 + 32 + d] = f2bf(v - bf2f(h));
  }
  gbar(A.cnt, 256*(++nb));

  // P0: attend layer1 step0 (h=0)
  if (bid >= 128 && bid < 160) attend_phase(A, 0, 0, bid-128, sm);
  gbar(A.cnt, 256*(++nb));

  for (int s = 0; s < NSTEP; ++s){
    const int p = s&1, pn = p^1;
    // P1: G1(s) || att2(s) || att3(s)
    if (bid < 128)        gemm_phase(A, 0, p, pn, sm);
    else if (bid < 160)   attend_phase(A, 1, p, bid-128, sm);
    else if (bid < 192)   attend_phase(A, 2, p, bid-160, sm);
    gbar(A.cnt, 256*(++nb));
    // P2: G2(s) || att1(s+1)
    if (bid < 128)        gemm_phase(A, 1, p, pn, sm);
    else if (bid < 160)   attend_phase(A, 0, pn, bid-128, sm);
    gbar(A.cnt, 256*(++nb));
    // P3: G3(s)
    if (bid < 128)        gemm_phase(A, 2, p, pn, sm);
    gbar(A.cnt, 256*(++nb));
    // P4: y(s) -> dout, prev -> l0 plane parity pn
    if (bid >= 128 && bid < 160) out_phase(A, pn, s, bid-128, sm);
    gbar(A.cnt, 256*(++nb));
  }
}

// ---------------------------------------------------------------------------
extern "C" void kernel_launch(void* const* d_in, const int* in_sizes, int n_in,
                              void* d_out, int out_size, void* d_ws, size_t ws_size,
                              hipStream_t stream) {
  const float* x    = (const float*)d_in[0];
  const float* w_c1 = (const float*)d_in[1];
  const float* b_c1 = (const float*)d_in[2];
  const float* w_c2 = (const float*)d_in[3];
  const float* b_c2 = (const float*)d_in[4];
  const float* w_c3 = (const float*)d_in[5];
  const float* b_c3 = (const float*)d_in[6];

  SeqArgs A;
  A.x     = x;
  A.wa[0] = (const float*)d_in[7];
  A.wa[1] = (const float*)d_in[9];
  A.wa[2] = (const float*)d_in[11];
  const float* wih1 = (const float*)d_in[13];
  const float* whh1 = (const float*)d_in[14];
  const float* bih1 = (const float*)d_in[15];
  const float* bhh1 = (const float*)d_in[16];
  const float* wih2 = (const float*)d_in[17];
  const float* whh2 = (const float*)d_in[18];
  const float* bih2 = (const float*)d_in[19];
  const float* bhh2 = (const float*)d_in[20];
  const float* wih3 = (const float*)d_in[21];
  const float* whh3 = (const float*)d_in[22];
  const float* bih3 = (const float*)d_in[23];
  const float* bhh3 = (const float*)d_in[24];
  A.wout = (const float*)d_in[25];
  A.bout = (const float*)d_in[26];
  A.dout = (float*)d_out;

  char* base = (char*)d_ws;
  size_t off = 0;
  auto alloc = [&](size_t bytes)->char*{
    char* pp = base + off; off = (off + bytes + 255) & ~(size_t)255; return pp;
  };

  u16* enc = (u16*)alloc((size_t)BB*LL3*CC3*2);            // 4.14 MB
  A.enc  = enc;
  A.hbuf = (float*)alloc((size_t)3*2*BB*HH*4);             // 0.79 MB
  A.cbuf = (float*)alloc((size_t)3*BB*HH*4);               // 0.39 MB
  for (int l=0;l<3;++l){
    size_t kin = (l==0)? K0 : K12;
    for (int par=0; par<2; ++par)
      for (int hl=0; hl<2; ++hl)
        A.pl[l][par][hl] = (u16*)alloc((size_t)BB*kin*2);
  }
  float* bs0 = (float*)alloc(4096*4);
  float* bs1 = (float*)alloc(4096*4);
  float* bs2 = (float*)alloc(4096*4);
  A.bsum[0]=bs0; A.bsum[1]=bs1; A.bsum[2]=bs2;
  A.cnt  = (u32*)alloc(512);
  u16 *wp[6];
  wp[0] = (u16*)alloc((size_t)4096*K0*2);                  // 9.18 MB
  wp[1] = (u16*)alloc((size_t)4096*K0*2);
  wp[2] = (u16*)alloc((size_t)4096*K12*2);                 // 17.04 MB
  wp[3] = (u16*)alloc((size_t)4096*K12*2);
  wp[4] = (u16*)alloc((size_t)4096*K12*2);
  wp[5] = (u16*)alloc((size_t)4096*K12*2);
  A.wwh[0]=wp[0]; A.wwl[0]=wp[1];
  A.wwh[1]=wp[2]; A.wwl[1]=wp[3];
  A.wwh[2]=wp[4]; A.wwl[2]=wp[5];
  // total ~93.2 MB

  // conv temps alias the layer-1 weight buffers (preps run after convs)
  float* r1 = (float*)wp[0];                         // 2.09 MB < 9.18 MB
  float* r2 = (float*)(((char*)wp[0]) + 2095104);    // 4.17 MB, still in wp[0]

  conv1_kernel<<<(BB*LL1+255)/256, 256, 0, stream>>>(x, w_c1, b_c1, r1);
  conv2_kernel<<<(BB*LL2+255)/256, 256, 0, stream>>>(r1, w_c2, b_c2, r2);
  conv3_kernel<<<(BB*LL3+255)/256, 256, 0, stream>>>(r2, w_c3, b_c3, enc);
  prep_kernel<<<2048, 256, 0, stream>>>(wih1, whh1, wp[0], wp[1],   96, K0);
  prep_kernel<<<2048, 256, 0, stream>>>(wih2, whh2, wp[2], wp[3], 1056, K12);
  prep_kernel<<<2048, 256, 0, stream>>>(wih3, whh3, wp[4], wp[5], 1056, K12);
  bsum_kernel<<<48, 256, 0, stream>>>(bih1,bhh1,bih2,bhh2,bih3,bhh3, bs0,bs1,bs2);
  barinit_kernel<<<1, 256, 0, stream>>>(A.cnt);

  void* params[] = { (void*)&A };
  hipLaunchCooperativeKernel((const void*)seq_kernel, dim3(256), dim3(1024),
                             params, 0, stream);
}